// Round 7
// baseline (319.502 us; speedup 1.0000x reference)
//
#include <hip/hip_runtime.h>
#include <hip/hip_bf16.h>

// Problem constants
#define BB 256
#define TT 1024
#define II 128
#define HH 64

// 2/ln2 folded into M+/M-, W_in and biases at prep time, so the recurrence
// computes tanh(x) as 1 - 2/(1+exp2(acc)) with no per-step pre-multiply.
#define PRESCALE 2.8853900817779268f

typedef float    f32x4_t __attribute__((ext_vector_type(4)));
typedef _Float16 h16x2   __attribute__((ext_vector_type(2)));
typedef _Float16 h16x4   __attribute__((ext_vector_type(4)));
typedef _Float16 h16x8   __attribute__((ext_vector_type(8)));
typedef __fp16   p16x2   __attribute__((ext_vector_type(2)));

union UH2 { unsigned u; h16x2 h; p16x2 p; };
union U4H8 { uint4 u; h16x8 h; };
union B128 { uint4 u; h16x2 h[4]; };

#if __has_builtin(__builtin_amdgcn_fdot2)
__device__ __forceinline__ float fdot2f(h16x2 a, h16x2 b, float c){
  return __builtin_amdgcn_fdot2(a, b, c, false);
}
#else
__device__ __forceinline__ float fdot2f(h16x2 a, h16x2 b, float c){
  return __builtin_fmaf((float)a[1], (float)b[1], __builtin_fmaf((float)a[0], (float)b[0], c));
}
#endif

// half_swap: value of v from lane (i ^ 32).
// permlane32_swap(v, v) returns {r0, r1} where per-lane {r0, r1} = {v, v_xor32}
// in an orientation-dependent order (R4 failed by picking the wrong one).
// r0 ^ r1 ^ v is exact at the bit level and recovers v_xor32 REGARDLESS of
// orientation. Compiles to permlane32_swap + v_xor3_b32. (Verified in R5.)
#if __has_builtin(__builtin_amdgcn_permlane32_swap)
__device__ __forceinline__ float half_swap(float v){
  unsigned vu = __float_as_uint(v);
  auto r = __builtin_amdgcn_permlane32_swap(vu, vu, false, false);
  return __uint_as_float(((unsigned)r[0]) ^ ((unsigned)r[1]) ^ vu);
}
#else
__device__ __forceinline__ float half_swap(float v){
  return __shfl_xor(v, 32, 64);
}
#endif

// ---------------------------------------------------------------------------
// Workspace layout:
//   wsf (f32)  @ 0      [4160]: only [4096..4159] used: combined bias[64] x PRESCALE
//   whf (u32)  @ 16640  [1024]: M+/M- 32x32 rows as packed f16x2 pairs:
//                               lane<32 -> M+ row lane; lane>=32 -> M- row lane-32
//   wsb (u16)  @ 24832  [8192]: W_in f16 MFMA B-fragments, frag-ready (x PRESCALE)
//
// Z2 block-diagonalization (verified R5): W h = [M+ s + M- d ; M+ s - M- d],
//   s = h_lo + h_hi, d = h_lo - h_hi.
// R6/R7: the consumer carries r = rcp(1+2^a) instead of h = 1-2r:
//   s = 2 - 2(r_lo + r_hi), d = 2(r_hi - r_lo)  -> one serial fma removed.
// ---------------------------------------------------------------------------
__global__ void k_prep(const float* __restrict__ Ap, const float* __restrict__ Am,
                       const float* __restrict__ Winw,
                       const float* __restrict__ Winb, const float* __restrict__ bias,
                       float* __restrict__ wsf, unsigned* __restrict__ whf,
                       unsigned short* __restrict__ wsb){
  const int tid = threadIdx.x;
  if (tid < 64) wsf[4096 + tid] = (Winb[tid] + bias[tid]) * PRESCALE;
  // M+/M- packed rows
  for (int e = tid; e < 1024; e += 256){
    int lane = e >> 4, jp = e & 15, row = lane & 31, j = 2*jp;
    float v0, v1;
    if (lane < 32){
      v0 = 0.25f*PRESCALE*(Ap[row*64+j]     + Ap[row*64+j+32]     + Ap[(row+32)*64+j]     + Ap[(row+32)*64+j+32]);
      v1 = 0.25f*PRESCALE*(Ap[row*64+j+1]   + Ap[row*64+j+33]     + Ap[(row+32)*64+j+1]   + Ap[(row+32)*64+j+33]);
    } else {
      v0 = 0.25f*PRESCALE*(Am[row*64+j]     - Am[row*64+j+32]     - Am[(row+32)*64+j]     + Am[(row+32)*64+j+32]);
      v1 = 0.25f*PRESCALE*(Am[row*64+j+1]   - Am[row*64+j+33]     - Am[(row+32)*64+j+1]   + Am[(row+32)*64+j+33]);
    }
    UH2 p;
    p.h[0] = (_Float16)v0;
    p.h[1] = (_Float16)v1;
    whf[e] = p.u;
  }
  for (int e = tid; e < 8192; e += 256){
    int j = e & 7, lane = (e >> 3) & 63, fidx = e >> 9;
    int ks = fidx >> 2, nt = fidx & 3, l15 = lane & 15, q = lane >> 4;
    union { _Float16 f; unsigned short s; } cv;
    cv.f = (_Float16)(Winw[(nt*16 + l15)*II + ks*32 + q*8 + j] * PRESCALE);
    wsb[e] = cv.s;
  }
}

// ---------------------------------------------------------------------------
// Fused producer/consumer kernel: one block per batch (256 blocks x 256 thr).
//   Producers (waves 1..3): 64 t-tiles (16 rows) round-robin — unchanged.
//   Consumer (wave 0): Z2-split recurrence, r-carried. Per step:
//     rsw = half_swap(r); t = fma(rsw,sgn,r); sd = fma(t,cm,cp)
//       (lo: s = 2-2(r+rsw); hi: d = 2(r-rsw))
//     DPP-pair-pack sd -> asm ds_write_b32 (all lanes)
//     -> 4 asm ds_read_b128 (uniform addr per half)
//     -> asm s_waitcnt lgkmcnt(0) + memory clobber + sched_barrier(0)
//        (rule-#18 pattern: the sched_barrier stops register-only fdot2s
//         hoisting above the wait; tied-operand data edges don't compile)
//     16 fdot2 -> z ; half_swap(z) -> a = fma(z,sgn,zsw) + u
//     r = rcp(1 + exp2(a))
// DS ops from one wave execute in order at the LDS, so the read needs no
// wait on the write; volatile asms preserve mutual program order.
// ---------------------------------------------------------------------------
__global__ __launch_bounds__(256, 1) void k_fused(const float* __restrict__ x,
                                                  const float* __restrict__ wsf,
                                                  const unsigned* __restrict__ whf,
                                                  const unsigned short* __restrict__ wsb,
                                                  const float* __restrict__ Wout,
                                                  const float* __restrict__ Woutb,
                                                  float* __restrict__ out){
  extern __shared__ unsigned char smem[];
  unsigned short* Us    = (unsigned short*)smem;            // 128 KB U buffer
  unsigned*       flags = (unsigned*)(smem + 131072);       // 64 tile flags
  unsigned*       Hb    = (unsigned*)(smem + 131072 + 256); // 256B sd broadcast

  const int b    = blockIdx.x;
  const int tid  = threadIdx.x;
  const int lane = tid & 63;
  const int wave = tid >> 6;
  const int l15  = lane & 15;
  const int q    = lane >> 4;

  if (tid < 64) flags[tid] = 0u;
  __syncthreads();

  if (wave != 0){
    // ---------------- Producers: waves 1..3 (unchanged, proven) ------------
    h16x8 bfr[4][4]; // [ks][nt]
    #pragma unroll
    for (int ks = 0; ks < 4; ++ks)
      #pragma unroll
      for (int nt = 0; nt < 4; ++nt)
        bfr[ks][nt] = *(const h16x8*)(wsb + ((ks*4 + nt)*64 + lane)*8);

    float bcv[4];
    #pragma unroll
    for (int nt = 0; nt < 4; ++nt) bcv[nt] = wsf[4096 + nt*16 + l15];

    const float* xb = x + (long)b * (TT * II);

    #pragma unroll 1
    for (int tile = wave - 1; tile < 64; tile += 3){
      const int trow = tile * 16;
      const float* xa = xb + (trow + l15) * II + q*8;
      h16x8 afr[4];
      #pragma unroll
      for (int ks = 0; ks < 4; ++ks){
        float4 a0 = *(const float4*)(xa + ks*32);
        float4 a1 = *(const float4*)(xa + ks*32 + 4);
        U4H8 v;
        UH2 p0, p1, p2, p3;
        p0.p = __builtin_amdgcn_cvt_pkrtz(a0.x, a0.y);
        p1.p = __builtin_amdgcn_cvt_pkrtz(a0.z, a0.w);
        p2.p = __builtin_amdgcn_cvt_pkrtz(a1.x, a1.y);
        p3.p = __builtin_amdgcn_cvt_pkrtz(a1.z, a1.w);
        v.u.x = p0.u; v.u.y = p1.u; v.u.z = p2.u; v.u.w = p3.u;
        afr[ks] = v.h;
      }
      f32x4_t acc[4];
      #pragma unroll
      for (int nt = 0; nt < 4; ++nt){
        acc[nt][0]=bcv[nt]; acc[nt][1]=bcv[nt]; acc[nt][2]=bcv[nt]; acc[nt][3]=bcv[nt];
      }
      #pragma unroll
      for (int ks = 0; ks < 4; ++ks){
        #pragma unroll
        for (int nt = 0; nt < 4; ++nt){
          acc[nt] = __builtin_amdgcn_mfma_f32_16x16x32_f16(afr[ks], bfr[ks][nt], acc[nt], 0, 0, 0);
        }
      }
      // acc[nt][r]: h = nt*16 + l15, t = trow + q*4 + r  -> tg = tile*4 + q
      const int tg = tile*4 + q;
      #pragma unroll
      for (int nt = 0; nt < 4; ++nt){
        UH2 lo, hi;
        lo.p = __builtin_amdgcn_cvt_pkrtz(acc[nt][0], acc[nt][1]);
        hi.p = __builtin_amdgcn_cvt_pkrtz(acc[nt][2], acc[nt][3]);
        uint2 pk; pk.x = lo.u; pk.y = hi.u;
        *(uint2*)&Us[(tg*64 + nt*16 + l15) * 4] = pk;
      }
      __threadfence_block();  // wave-level lgkmcnt drain: all lanes' ds_writes done
      if (lane == 0)
        __hip_atomic_store(&flags[tile], 1u, __ATOMIC_RELEASE, __HIP_MEMORY_SCOPE_WORKGROUP);
    }
    return;
  }

  // ---------------- Consumer: wave 0 ----------------
  // M+/M- row pairs for this lane (16 pairs = 32 f16)
  h16x2 w[16];
  {
    const uint4* wr = (const uint4*)(whf + lane * 16);
    #pragma unroll
    for (int j4 = 0; j4 < 4; ++j4){
      uint4 v = wr[j4];
      UH2 c0, c1, c2, c3;
      c0.u = v.x; c1.u = v.y; c2.u = v.z; c3.u = v.w;
      w[4*j4+0] = c0.h; w[4*j4+1] = c1.h; w[4*j4+2] = c2.h; w[4*j4+3] = c3.h;
    }
  }

  const bool  lo    = (lane < 32);
  const float sgn   = lo ? 1.0f : -1.0f;
  const float cm    = lo ? -2.0f : 2.0f;   // sd = fma(t, cm, cp)
  const float cp    = lo ?  2.0f : 0.0f;
  const int   hslot = (lane >> 1) + (lane & 1) * 32;   // all-lane write slot (0..63)
  // LDS byte offsets for asm DS ops (low 32 bits of a generic LDS pointer
  // are the LDS offset on amdgcn).
  const unsigned hb_off = (unsigned)(uintptr_t)(void*)Hb;
  const unsigned waddr  = hb_off + (unsigned)hslot * 4u;
  const unsigned raddr  = hb_off + (unsigned)((lane & 32) * 2); // +0B (s) / +64B (d)

  // Wait for tile 0 before the initial u loads.
  while (!__hip_atomic_load(&flags[0], __ATOMIC_ACQUIRE, __HIP_MEMORY_SCOPE_WORKGROUP)) {}

  const h16x4* Ul = (const h16x4*)Us;  // entry index = tg*64 + lane
  h16x4 uc = Ul[0*64 + lane];
  h16x4 u1 = Ul[1*64 + lane];

  float r = 0.5f;                      // h = 1 - 2r = 0
  int last_ready = 0;
  #pragma unroll 1
  for (int tile = 0; tile < 64; ++tile){
    int wt = tile + 1; if (wt > 63) wt = 63;
    if (wt > last_ready){
      while (!__hip_atomic_load(&flags[wt], __ATOMIC_ACQUIRE, __HIP_MEMORY_SCOPE_WORKGROUP)) {}
      last_ready = wt;
    }
    #pragma unroll
    for (int tgl = 0; tgl < 4; ++tgl){
      const int tg = tile*4 + tgl;
      int tp = tg + 2; if (tp > TT/4 - 1) tp = TT/4 - 1;
      h16x4 u2 = Ul[tp*64 + lane];
      float ug0 = (float)uc[0], ug1 = (float)uc[1], ug2 = (float)uc[2], ug3 = (float)uc[3];
      #pragma unroll
      for (int g = 0; g < 4; ++g){
        float ugv = (g==0) ? ug0 : (g==1) ? ug1 : (g==2) ? ug2 : ug3;
        // sd from carried r:  lo: s = 2 - 2(r + rsw) ; hi: d = 2(r - rsw)
        float rsw = half_swap(r);
        float t   = __builtin_fmaf(rsw, sgn, r);
        float sd  = __builtin_fmaf(t, cm, cp);
        // pack (sd_2k, sd_2k+1) on even lanes via DPP quad-perm [1,0,3,2]
        unsigned nbu = (unsigned)__builtin_amdgcn_mov_dpp(__float_as_uint(sd), 0xB1, 0xF, 0xF, true);
        UH2 hp; hp.p = __builtin_amdgcn_cvt_pkrtz(sd, __uint_as_float(nbu)); // valid on even lanes
        // Broadcast via DS pipe: write + 4 uniform b128 reads, no intermediate
        // drain (same-wave DS ops execute in order at the LDS). Rule-#18
        // fence: waitcnt (memory clobber) + sched_barrier(0) so the
        // register-only fdot2s cannot hoist above the wait.
        B128 hv0, hv1, hv2, hv3;
        asm volatile("ds_write_b32 %0, %1" :: "v"(waddr), "v"(hp.u));
        asm volatile("ds_read_b128 %0, %1 offset:0"  : "=v"(hv0.u) : "v"(raddr));
        asm volatile("ds_read_b128 %0, %1 offset:16" : "=v"(hv1.u) : "v"(raddr));
        asm volatile("ds_read_b128 %0, %1 offset:32" : "=v"(hv2.u) : "v"(raddr));
        asm volatile("ds_read_b128 %0, %1 offset:48" : "=v"(hv3.u) : "v"(raddr));
        asm volatile("s_waitcnt lgkmcnt(0)" ::: "memory");
        __builtin_amdgcn_sched_barrier(0);
        float a0 = 0.0f, a1 = 0.0f, a2 = 0.0f, a3 = 0.0f;
        #pragma unroll
        for (int jp = 0; jp < 4; ++jp){
          a0 = fdot2f(w[jp+ 0], hv0.h[jp], a0);
          a1 = fdot2f(w[jp+ 4], hv1.h[jp], a1);
          a2 = fdot2f(w[jp+ 8], hv2.h[jp], a2);
          a3 = fdot2f(w[jp+12], hv3.h[jp], a3);
        }
        float z = (a0 + a1) + (a2 + a3);     // z1 on lo half, z2 on hi half
        // recombine: a_lo = z1 + z2 + u ; a_hi = z1 - z2 + u
        float zsw = half_swap(z);
        float a = __builtin_fmaf(z, sgn, zsw) + ugv;
        float e = __builtin_amdgcn_exp2f(a);
        r = __builtin_amdgcn_rcpf(1.0f + e);
      }
      uc = u1; u1 = u2;
    }
  }

  // Epilogue: h = 1 - 2r ; predictions[b] = W_out @ h + W_out_b ; hidden[b] = h
  float h = __builtin_fmaf(-2.0f, r, 1.0f);
  unsigned hu = __float_as_uint(h);
  float p0 = Woutb[lane];
  float p1 = Woutb[lane + 64];
  #pragma unroll 8
  for (int j = 0; j < 64; ++j){
    float hj = __uint_as_float(__builtin_amdgcn_readlane(hu, j));
    p0 = __builtin_fmaf(Wout[lane * HH + j],        hj, p0);
    p1 = __builtin_fmaf(Wout[(lane + 64) * HH + j], hj, p1);
  }
  out[b * 128 + lane]           = p0;
  out[b * 128 + 64 + lane]      = p1;
  out[BB * 128 + b * 64 + lane] = h;
}

// ---------------------------------------------------------------------------
extern "C" void kernel_launch(void* const* d_in, const int* in_sizes, int n_in,
                              void* d_out, int out_size, void* d_ws, size_t ws_size,
                              hipStream_t stream){
  const float* x     = (const float*)d_in[0];
  const float* Ap    = (const float*)d_in[1];
  const float* Am    = (const float*)d_in[2];
  const float* Winw  = (const float*)d_in[3];
  const float* Winb  = (const float*)d_in[4];
  const float* Woutw = (const float*)d_in[5];
  const float* Woutb = (const float*)d_in[6];
  const float* bias  = (const float*)d_in[7];

  float*          wsf = (float*)d_ws;
  unsigned*       whf = (unsigned*)((char*)d_ws + 16640);
  unsigned short* wsb = (unsigned short*)((char*)d_ws + 24832);

  float* out = (float*)d_out;

  hipFuncSetAttribute((const void*)k_fused,
                      hipFuncAttributeMaxDynamicSharedMemorySize, 131584);

  hipLaunchKernelGGL(k_prep,  dim3(1),   dim3(256), 0,      stream, Ap, Am, Winw, Winb, bias, wsf, whf, wsb);
  hipLaunchKernelGGL(k_fused, dim3(BB),  dim3(256), 131584, stream, x, wsf, whf, wsb, Woutw, Woutb, out);
}

// Round 9
// 292.105 us; speedup vs baseline: 1.0938x; 1.0938x over previous
//
#include <hip/hip_runtime.h>
#include <hip/hip_bf16.h>

// Problem constants
#define BB 256
#define TT 1024
#define II 128
#define HH 64

// 2/ln2 folded into G+/G-, W_in and biases at prep time, so the recurrence
// computes tanh(x) as 1 - 2/(1+exp2(acc)) with no per-step pre-multiply.
#define PRESCALE 2.8853900817779268f

typedef float    f32x4_t __attribute__((ext_vector_type(4)));
typedef _Float16 h16x2   __attribute__((ext_vector_type(2)));
typedef _Float16 h16x4   __attribute__((ext_vector_type(4)));
typedef _Float16 h16x8   __attribute__((ext_vector_type(8)));
typedef __fp16   p16x2   __attribute__((ext_vector_type(2)));

union UH2 { unsigned u; h16x2 h; p16x2 p; };
union U4H8 { uint4 u; h16x8 h; };
union B128 { uint4 u; h16x2 h[4]; };

#if __has_builtin(__builtin_amdgcn_fdot2)
__device__ __forceinline__ float fdot2f(h16x2 a, h16x2 b, float c){
  return __builtin_amdgcn_fdot2(a, b, c, false);
}
#else
__device__ __forceinline__ float fdot2f(h16x2 a, h16x2 b, float c){
  return __builtin_fmaf((float)a[1], (float)b[1], __builtin_fmaf((float)a[0], (float)b[0], c));
}
#endif

// permlane32_swap(v, v) -> {r0, r1}:
//   r0 = lo-half of v broadcast to both halves (lane i and lane 32+i get v[i])
//   r1 = hi-half of v broadcast to both halves (both get v[32+i])
// Orientation pinned by two independent sources: LLVM swap semantics
// (new_first[32+i] = old_second[i], new_second[i] = old_first[32+i]) and R4's
// failure signature (lo?r0:r1 returned own value). R5's xor3 identity
// (r0 ^ r1 ^ v = v_xor32) verified the pair contents on hardware.
__device__ __forceinline__ void half_pair(float v, float& blo, float& bhi){
#if __has_builtin(__builtin_amdgcn_permlane32_swap)
  unsigned vu = __float_as_uint(v);
  auto r = __builtin_amdgcn_permlane32_swap(vu, vu, false, false);
  blo = __uint_as_float((unsigned)r[0]);
  bhi = __uint_as_float((unsigned)r[1]);
#else
  float sw = __shfl_xor(v, 32, 64);
  bool lo = ((threadIdx.x & 63) < 32);
  blo = lo ? v : sw;
  bhi = lo ? sw : v;
#endif
}

// ---------------------------------------------------------------------------
// Workspace layout:
//   wsf (f32)  @ 0      [4160]: only [4096..4159] used:
//       combined bias[64] x PRESCALE + c-fold (c_i = 2*(M+ 1)_i x PRESCALE)
//   whf (u32)  @ 16640  [1024]: G+/G- 32x32 rows as packed f16x2 pairs:
//       lane<32 -> G+ row lane; lane>=32 -> G- row lane-32, G± = -2*M±*PRESC
//   wsb (u16)  @ 24832  [8192]: W_in f16 MFMA B-fragments, frag-ready (x PRESCALE)
//
// Z2 block-diagonalization (verified R5): W h = [M+ s + M- d ; M+ s - M- d],
//   s = h_lo + h_hi, d = h_lo - h_hi. With r-carry (h = 1-2r):
//   s = 2*1 - 2t (t = rL + rH), d = -2q (q = rL - rH).
//   lo dot: y = G+ t = z1 - c ; hi dot: y = G- q = z2  (exact)
//   a = y0 + sgn*y1 + (u + c)  -> r' = rcp(1 + exp2(a))
// ---------------------------------------------------------------------------
__global__ void k_prep(const float* __restrict__ Ap, const float* __restrict__ Am,
                       const float* __restrict__ Winw,
                       const float* __restrict__ Winb, const float* __restrict__ bias,
                       float* __restrict__ wsf, unsigned* __restrict__ whf,
                       unsigned short* __restrict__ wsb){
  const int tid = threadIdx.x;
  // combined bias with c-fold: c_i = 2 * sum_j M+_presc[i&31][j]
  //   = 0.5 * PRESCALE * sum_{j<64} (Ap[row][j] + Ap[row+32][j])
  if (tid < 64){
    int row = tid & 31;
    float cs = 0.0f;
    for (int j = 0; j < 64; ++j) cs += Ap[row*64 + j] + Ap[(row+32)*64 + j];
    wsf[4096 + tid] = (Winb[tid] + bias[tid]) * PRESCALE + 0.5f * PRESCALE * cs;
  }
  // G+/G- packed rows: G+ = -2*M+*PRESC, G- = -2*M-*PRESC (quarter-sum form)
  for (int e = tid; e < 1024; e += 256){
    int lane = e >> 4, jp = e & 15, row = lane & 31, j = 2*jp;
    float v0, v1;
    if (lane < 32){
      v0 = -0.5f*PRESCALE*(Ap[row*64+j]   + Ap[row*64+j+32] + Ap[(row+32)*64+j]   + Ap[(row+32)*64+j+32]);
      v1 = -0.5f*PRESCALE*(Ap[row*64+j+1] + Ap[row*64+j+33] + Ap[(row+32)*64+j+1] + Ap[(row+32)*64+j+33]);
    } else {
      v0 = -0.5f*PRESCALE*(Am[row*64+j]   - Am[row*64+j+32] - Am[(row+32)*64+j]   + Am[(row+32)*64+j+32]);
      v1 = -0.5f*PRESCALE*(Am[row*64+j+1] - Am[row*64+j+33] - Am[(row+32)*64+j+1] + Am[(row+32)*64+j+33]);
    }
    UH2 p;
    p.h[0] = (_Float16)v0;
    p.h[1] = (_Float16)v1;
    whf[e] = p.u;
  }
  for (int e = tid; e < 8192; e += 256){
    int j = e & 7, lane = (e >> 3) & 63, fidx = e >> 9;
    int ks = fidx >> 2, nt = fidx & 3, l15 = lane & 15, q = lane >> 4;
    union { _Float16 f; unsigned short s; } cv;
    cv.f = (_Float16)(Winw[(nt*16 + l15)*II + ks*32 + q*8 + j] * PRESCALE);
    wsb[e] = cv.s;
  }
}

// ---------------------------------------------------------------------------
// Fused producer/consumer kernel: one block per batch (256 blocks x 256 thr).
//   Producers (waves 1..3): 64 t-tiles (16 rows) round-robin — unchanged.
//   Consumer (wave 0): Z2-split recurrence, r-carried, affine-folded. Per step:
//     permlane32_swap(r) -> (r0, r1); val = fma(r1, sgn, r0)  (t lo / q hi)
//     cvt_f16 -> per-lane ds_write_b16 at byte 2*lane (conflict-free)
//     compiler fence (asm memory clobber + sched_barrier) — R5-proven; the
//       reads stay C++ loads so the compiler emits progressive lgkmcnt waits
//       (R7 showed hand-drained lgkmcnt(0) costs ~20 cyc/step)
//     4 uniform ds_read_b128 per half -> 16 fdot2 -> y
//     permlane32_swap(y) -> a = fma(y1, sgn, y0) + u' ; r = rcp(1+exp2(a))
// ---------------------------------------------------------------------------
__global__ __launch_bounds__(256, 1) void k_fused(const float* __restrict__ x,
                                                  const float* __restrict__ wsf,
                                                  const unsigned* __restrict__ whf,
                                                  const unsigned short* __restrict__ wsb,
                                                  const float* __restrict__ Wout,
                                                  const float* __restrict__ Woutb,
                                                  float* __restrict__ out){
  extern __shared__ unsigned char smem[];
  unsigned short* Us    = (unsigned short*)smem;            // 128 KB U buffer
  unsigned*       flags = (unsigned*)(smem + 131072);       // 64 tile flags
  unsigned short* Hw    = (unsigned short*)(smem + 131072 + 256); // 128B val broadcast

  const int b    = blockIdx.x;
  const int tid  = threadIdx.x;
  const int lane = tid & 63;
  const int wave = tid >> 6;
  const int l15  = lane & 15;
  const int q    = lane >> 4;

  if (tid < 64) flags[tid] = 0u;
  __syncthreads();

  if (wave != 0){
    // ---------------- Producers: waves 1..3 (unchanged, proven) ------------
    h16x8 bfr[4][4]; // [ks][nt]
    #pragma unroll
    for (int ks = 0; ks < 4; ++ks)
      #pragma unroll
      for (int nt = 0; nt < 4; ++nt)
        bfr[ks][nt] = *(const h16x8*)(wsb + ((ks*4 + nt)*64 + lane)*8);

    float bcv[4];
    #pragma unroll
    for (int nt = 0; nt < 4; ++nt) bcv[nt] = wsf[4096 + nt*16 + l15];

    const float* xb = x + (long)b * (TT * II);

    #pragma unroll 1
    for (int tile = wave - 1; tile < 64; tile += 3){
      const int trow = tile * 16;
      const float* xa = xb + (trow + l15) * II + q*8;
      h16x8 afr[4];
      #pragma unroll
      for (int ks = 0; ks < 4; ++ks){
        float4 a0 = *(const float4*)(xa + ks*32);
        float4 a1 = *(const float4*)(xa + ks*32 + 4);
        U4H8 v;
        UH2 p0, p1, p2, p3;
        p0.p = __builtin_amdgcn_cvt_pkrtz(a0.x, a0.y);
        p1.p = __builtin_amdgcn_cvt_pkrtz(a0.z, a0.w);
        p2.p = __builtin_amdgcn_cvt_pkrtz(a1.x, a1.y);
        p3.p = __builtin_amdgcn_cvt_pkrtz(a1.z, a1.w);
        v.u.x = p0.u; v.u.y = p1.u; v.u.z = p2.u; v.u.w = p3.u;
        afr[ks] = v.h;
      }
      f32x4_t acc[4];
      #pragma unroll
      for (int nt = 0; nt < 4; ++nt){
        acc[nt][0]=bcv[nt]; acc[nt][1]=bcv[nt]; acc[nt][2]=bcv[nt]; acc[nt][3]=bcv[nt];
      }
      #pragma unroll
      for (int ks = 0; ks < 4; ++ks){
        #pragma unroll
        for (int nt = 0; nt < 4; ++nt){
          acc[nt] = __builtin_amdgcn_mfma_f32_16x16x32_f16(afr[ks], bfr[ks][nt], acc[nt], 0, 0, 0);
        }
      }
      // acc[nt][r]: h = nt*16 + l15, t = trow + q*4 + r  -> tg = tile*4 + q
      const int tg = tile*4 + q;
      #pragma unroll
      for (int nt = 0; nt < 4; ++nt){
        UH2 lo, hi;
        lo.p = __builtin_amdgcn_cvt_pkrtz(acc[nt][0], acc[nt][1]);
        hi.p = __builtin_amdgcn_cvt_pkrtz(acc[nt][2], acc[nt][3]);
        uint2 pk; pk.x = lo.u; pk.y = hi.u;
        *(uint2*)&Us[(tg*64 + nt*16 + l15) * 4] = pk;
      }
      __threadfence_block();  // wave-level lgkmcnt drain: all lanes' ds_writes done
      if (lane == 0)
        __hip_atomic_store(&flags[tile], 1u, __ATOMIC_RELEASE, __HIP_MEMORY_SCOPE_WORKGROUP);
    }
    return;
  }

  // ---------------- Consumer: wave 0 ----------------
  // G+/G- row pairs for this lane (16 pairs = 32 f16)
  h16x2 w[16];
  {
    const uint4* wr = (const uint4*)(whf + lane * 16);
    #pragma unroll
    for (int j4 = 0; j4 < 4; ++j4){
      uint4 v = wr[j4];
      UH2 c0, c1, c2, c3;
      c0.u = v.x; c1.u = v.y; c2.u = v.z; c3.u = v.w;
      w[4*j4+0] = c0.h; w[4*j4+1] = c1.h; w[4*j4+2] = c2.h; w[4*j4+3] = c3.h;
    }
  }

  const bool  lo  = (lane < 32);
  const float sgn = lo ? 1.0f : -1.0f;
  const uint4* Hr = (const uint4*)((const unsigned char*)Hw + (lane & 32) * 2); // +0B (t) / +64B (q)

  // Wait for tile 0 before the initial u loads.
  while (!__hip_atomic_load(&flags[0], __ATOMIC_ACQUIRE, __HIP_MEMORY_SCOPE_WORKGROUP)) {}

  const h16x4* Ul = (const h16x4*)Us;  // entry index = tg*64 + lane
  h16x4 uc = Ul[0*64 + lane];
  h16x4 u1 = Ul[1*64 + lane];

  float r = 0.5f;                      // h = 1 - 2r = 0
  int last_ready = 0;
  #pragma unroll 1
  for (int tile = 0; tile < 64; ++tile){
    int wt = tile + 1; if (wt > 63) wt = 63;
    if (wt > last_ready){
      while (!__hip_atomic_load(&flags[wt], __ATOMIC_ACQUIRE, __HIP_MEMORY_SCOPE_WORKGROUP)) {}
      last_ready = wt;
    }
    #pragma unroll
    for (int tgl = 0; tgl < 4; ++tgl){
      const int tg = tile*4 + tgl;
      int tp = tg + 2; if (tp > TT/4 - 1) tp = TT/4 - 1;
      h16x4 u2 = Ul[tp*64 + lane];
      float ug0 = (float)uc[0], ug1 = (float)uc[1], ug2 = (float)uc[2], ug3 = (float)uc[3];
      #pragma unroll
      for (int g = 0; g < 4; ++g){
        float ugv = (g==0) ? ug0 : (g==1) ? ug1 : (g==2) ? ug2 : ug3;
        // val: lo lane i -> t_i = rL_i + rH_i ; hi lane i -> q_i = rL_i - rH_i
        float r0, r1;
        half_pair(r, r0, r1);
        float val = __builtin_fmaf(r1, sgn, r0);
        _Float16 vh = (_Float16)val;
        Hw[lane] = *(unsigned short*)&vh;   // ds_write_b16 at byte 2*lane
        // R5-proven fence: compiler must not hoist the uniform reads above
        // the write; hardware DS pipe is in-order per wave. Reads remain C++
        // loads so the compiler emits progressive lgkmcnt waits (R7 lesson).
        __asm__ volatile("" ::: "memory");
        __builtin_amdgcn_sched_barrier(0);
        // read back this half's 32 values: 4 uniform-address b128 broadcasts
        B128 hv[4];
        #pragma unroll
        for (int rr = 0; rr < 4; ++rr) hv[rr].u = Hr[rr];
        float a0 = 0.0f, a1 = 0.0f, a2 = 0.0f, a3 = 0.0f;
        #pragma unroll
        for (int jp = 0; jp < 4; ++jp){
          a0 = fdot2f(w[jp+ 0], hv[0].h[jp], a0);
          a1 = fdot2f(w[jp+ 4], hv[1].h[jp], a1);
          a2 = fdot2f(w[jp+ 8], hv[2].h[jp], a2);
          a3 = fdot2f(w[jp+12], hv[3].h[jp], a3);
        }
        float y = (a0 + a1) + (a2 + a3);   // lo: z1 - c ; hi: z2 (exact)
        // recombine: a = y0 + sgn*y1 + u'   (u' has the +c fold)
        float y0, y1;
        half_pair(y, y0, y1);
        float a = __builtin_fmaf(y1, sgn, y0) + ugv;
        float e = __builtin_amdgcn_exp2f(a);
        r = __builtin_amdgcn_rcpf(1.0f + e);
      }
      uc = u1; u1 = u2;
    }
  }

  // Epilogue: h = 1 - 2r ; predictions[b] = W_out @ h + W_out_b ; hidden[b] = h
  float h = __builtin_fmaf(-2.0f, r, 1.0f);
  unsigned hu = __float_as_uint(h);
  float p0 = Woutb[lane];
  float p1 = Woutb[lane + 64];
  #pragma unroll 8
  for (int j = 0; j < 64; ++j){
    float hj = __uint_as_float(__builtin_amdgcn_readlane(hu, j));
    p0 = __builtin_fmaf(Wout[lane * HH + j],        hj, p0);
    p1 = __builtin_fmaf(Wout[(lane + 64) * HH + j], hj, p1);
  }
  out[b * 128 + lane]           = p0;
  out[b * 128 + 64 + lane]      = p1;
  out[BB * 128 + b * 64 + lane] = h;
}

// ---------------------------------------------------------------------------
extern "C" void kernel_launch(void* const* d_in, const int* in_sizes, int n_in,
                              void* d_out, int out_size, void* d_ws, size_t ws_size,
                              hipStream_t stream){
  const float* x     = (const float*)d_in[0];
  const float* Ap    = (const float*)d_in[1];
  const float* Am    = (const float*)d_in[2];
  const float* Winw  = (const float*)d_in[3];
  const float* Winb  = (const float*)d_in[4];
  const float* Woutw = (const float*)d_in[5];
  const float* Woutb = (const float*)d_in[6];
  const float* bias  = (const float*)d_in[7];

  float*          wsf = (float*)d_ws;
  unsigned*       whf = (unsigned*)((char*)d_ws + 16640);
  unsigned short* wsb = (unsigned short*)((char*)d_ws + 24832);

  float* out = (float*)d_out;

  hipFuncSetAttribute((const void*)k_fused,
                      hipFuncAttributeMaxDynamicSharedMemorySize, 131456);

  hipLaunchKernelGGL(k_prep,  dim3(1),   dim3(256), 0,      stream, Ap, Am, Winw, Winb, bias, wsf, whf, wsb);
  hipLaunchKernelGGL(k_fused, dim3(BB),  dim3(256), 131456, stream, x, wsf, whf, wsb, Woutw, Woutb, out);
}